// Round 8
// baseline (1837.768 us; speedup 1.0000x reference)
//
#include <hip/hip_runtime.h>
#include <cfloat>
#include <climits>

#define TPB 256

// ---------------------------------------------------------------------------
// Numerics contract (rounds 3-7 PASSED): every matmul output is a
// k-sequential single-accumulator fp32 fmaf chain (k ascending), bias via
// __fadd_rn (encoder), norms via numpy pairwise order,
// d = fl(fl(nl+ne) - fl(2*dot)), argmin strict-< with first-index ties.
// Round-8: enc/dec -> 32-row blocks TPB=512 with small LDS (enc aliases
// sH2 onto dead sX) -> 2 blocks/CU = 16 waves/CU (2x round 7's TLP for the
// L2-latency-exposed weight streams). vq unchanged. Chains unchanged.
// ---------------------------------------------------------------------------

// =================== prep: W -> WT  and  emb -> embT + En ==================
__global__ __launch_bounds__(TPB) void prep_kernel(
    const float* __restrict__ W1, const float* __restrict__ W2,
    const float* __restrict__ W3, const float* __restrict__ U1,
    const float* __restrict__ U2, const float* __restrict__ Umu,
    const float* __restrict__ Ulv, float* __restrict__ wt,
    const float* __restrict__ emb, float* __restrict__ embT,
    float* __restrict__ En) {
  __shared__ float sB[64 * 68];
  const int b = blockIdx.x;
  const int t = threadIdx.x;
  if (b < 44) {  // weight transpose: WT[k][n] = W[n][k], 64x64 tiles
    const float* src; int R, C, lt; float* dst;
    if (b < 8)       { src = W1;  R = 256; C = 128; dst = wt;          lt = b; }
    else if (b < 16) { src = W2;  R = 128; C = 256; dst = wt + 32768;  lt = b - 8; }
    else if (b < 18) { src = W3;  R = 64;  C = 128; dst = wt + 65536;  lt = b - 16; }
    else if (b < 20) { src = U1;  R = 128; C = 64;  dst = wt + 73728;  lt = b - 18; }
    else if (b < 28) { src = U2;  R = 256; C = 128; dst = wt + 81920;  lt = b - 20; }
    else if (b < 36) { src = Umu; R = 128; C = 256; dst = wt + 114688; lt = b - 28; }
    else             { src = Ulv; R = 128; C = 256; dst = wt + 147456; lt = b - 36; }
    const int tiles_r = R >> 6;
    const int r0 = (lt % tiles_r) << 6, c0 = (lt / tiles_r) << 6;
    for (int v = t; v < 1024; v += TPB) {
      const int c4 = v & 15, r = v >> 4;
      const float4 w = *reinterpret_cast<const float4*>(
          src + (size_t)(r0 + r) * C + c0 + 4 * c4);
      *reinterpret_cast<float4*>(&sB[r * 68 + 4 * c4]) = w;
    }
    __syncthreads();
    for (int v = t; v < 1024; v += TPB) {
      const int r4 = v & 15, c = v >> 4;
      float4 o;
      o.x = sB[(4 * r4 + 0) * 68 + c];
      o.y = sB[(4 * r4 + 1) * 68 + c];
      o.z = sB[(4 * r4 + 2) * 68 + c];
      o.w = sB[(4 * r4 + 3) * 68 + c];
      *reinterpret_cast<float4*>(dst + (size_t)(c0 + c) * R + r0 + 4 * r4) = o;
    }
  } else {  // emb transpose + numpy-pairwise ||e||^2
    const int c0 = (b - 44) * 64;
    for (int v = t; v < 1024; v += TPB) {
      const int d4 = v & 15, r = v >> 4;
      const float4 e = *reinterpret_cast<const float4*>(
          emb + (size_t)(c0 + r) * 64 + 4 * d4);
      *reinterpret_cast<float4*>(&sB[r * 68 + 4 * d4]) = e;
    }
    __syncthreads();
    if (t < 64) {
      const float* row = &sB[t * 68];
      float q[8];
#pragma unroll
      for (int j = 0; j < 8; ++j) q[j] = __fmul_rn(row[j], row[j]);
#pragma unroll
      for (int m = 1; m < 8; ++m)
#pragma unroll
        for (int j = 0; j < 8; ++j) {
          const float v = row[m * 8 + j];
          q[j] = __fadd_rn(q[j], __fmul_rn(v, v));
        }
      En[c0 + t] = __fadd_rn(
          __fadd_rn(__fadd_rn(q[0], q[1]), __fadd_rn(q[2], q[3])),
          __fadd_rn(__fadd_rn(q[4], q[5]), __fadd_rn(q[6], q[7])));
    }
    for (int v = t; v < 1024; v += TPB) {
      const int r4 = v & 15, d = v >> 4;
      float4 o;
      o.x = sB[(4 * r4 + 0) * 68 + d];
      o.y = sB[(4 * r4 + 1) * 68 + d];
      o.z = sB[(4 * r4 + 2) * 68 + d];
      o.w = sB[(4 * r4 + 3) * 68 + d];
      *reinterpret_cast<float4*>(embT + (size_t)d * 8192 + c0 + 4 * r4) = o;
    }
  }
}

// ================ fused encoder (32 rows, 512 thr, 55.3 KB) ================
// sH2 aliases sX (dead after L1) -> 2 blocks/CU = 16 waves/CU.
__global__ __launch_bounds__(512) void enc_fused(
    const float* __restrict__ x, const float* __restrict__ WT1,
    const float* __restrict__ WT2, const float* __restrict__ WT3,
    const float* __restrict__ b1, const float* __restrict__ b2,
    const float* __restrict__ b3, float* __restrict__ lat) {
  __shared__ float smem[128 * 36 + 256 * 36];
  float* sX = smem;             // [128k][36r]; reused as sH2 after L1
  float* sH1 = smem + 128 * 36; // [256k][36r]
  float* sH2 = smem;            // alias of sX
  const int t = threadIdx.x;
  const int m0 = blockIdx.x * 32;

  for (int v = t; v < 1024; v += 512) {  // stage x transposed
    const int k4 = v & 31, r = v >> 5;
    const float4 xv =
        *reinterpret_cast<const float4*>(x + (size_t)(m0 + r) * 128 + 4 * k4);
    float* dst = &sX[(4 * k4) * 36 + r];
    dst[0] = xv.x; dst[36] = xv.y; dst[72] = xv.z; dst[108] = xv.w;
  }
  __syncthreads();

  // L1: K=128, N=256. 32 colgroups (8 cols) x 16 rowgroups (2 rows)
  {
    const int cg8 = (t & 31) * 8, rg2 = (t >> 5) * 2;
    float acc[2][8] = {};
#pragma unroll 8
    for (int k = 0; k < 128; ++k) {
      const float2 a = *reinterpret_cast<const float2*>(&sX[k * 36 + rg2]);
      const float* wr = WT1 + (size_t)k * 256 + cg8;
      const float4 b0 = *reinterpret_cast<const float4*>(wr);
      const float4 b1v = *reinterpret_cast<const float4*>(wr + 4);
      const float av[2] = {a.x, a.y};
      const float bv[8] = {b0.x, b0.y, b0.z, b0.w, b1v.x, b1v.y, b1v.z, b1v.w};
#pragma unroll
      for (int i = 0; i < 2; ++i)
#pragma unroll
        for (int j = 0; j < 8; ++j) acc[i][j] = fmaf(av[i], bv[j], acc[i][j]);
    }
#pragma unroll
    for (int j = 0; j < 8; ++j) {
      const int col = cg8 + j;
      const float bj = b1[col];
#pragma unroll
      for (int i = 0; i < 2; ++i) {
        const float h = __fadd_rn(acc[i][j], bj);
        sH1[col * 36 + rg2 + i] = h > 0.f ? h : 0.f;
      }
    }
  }
  __syncthreads();

  // L2: K=256, N=128. 32 colgroups (4 cols) x 16 rowgroups (2 rows) -> sH2
  {
    const int cg4 = (t & 31) * 4, rg2 = (t >> 5) * 2;
    float acc[2][4] = {};
#pragma unroll 8
    for (int k = 0; k < 256; ++k) {
      const float2 a = *reinterpret_cast<const float2*>(&sH1[k * 36 + rg2]);
      const float4 bb =
          *reinterpret_cast<const float4*>(WT2 + (size_t)k * 128 + cg4);
      const float av[2] = {a.x, a.y};
      const float bv[4] = {bb.x, bb.y, bb.z, bb.w};
#pragma unroll
      for (int i = 0; i < 2; ++i)
#pragma unroll
        for (int j = 0; j < 4; ++j) acc[i][j] = fmaf(av[i], bv[j], acc[i][j]);
    }
    __syncthreads();  // sX fully read (L1 done for all waves) before overwrite
#pragma unroll
    for (int j = 0; j < 4; ++j) {
      const int col = cg4 + j;
      const float bj = b2[col];
#pragma unroll
      for (int i = 0; i < 2; ++i) {
        const float h = __fadd_rn(acc[i][j], bj);
        sH2[col * 36 + rg2 + i] = h > 0.f ? h : 0.f;
      }
    }
  }
  __syncthreads();

  // L3: K=128, N=64. 16 colgroups (4 cols) x 32 rowgroups (1 row) -> lat
  {
    const int cg4 = (t & 15) * 4, rg = t >> 4;
    float acc[4] = {};
#pragma unroll 8
    for (int k = 0; k < 128; ++k) {
      const float a = sH2[k * 36 + rg];
      const float4 bb =
          *reinterpret_cast<const float4*>(WT3 + (size_t)k * 64 + cg4);
      acc[0] = fmaf(a, bb.x, acc[0]);
      acc[1] = fmaf(a, bb.y, acc[1]);
      acc[2] = fmaf(a, bb.z, acc[2]);
      acc[3] = fmaf(a, bb.w, acc[3]);
    }
    float4 o;
    o.x = __fadd_rn(acc[0], b3[cg4 + 0]);
    o.y = __fadd_rn(acc[1], b3[cg4 + 1]);
    o.z = __fadd_rn(acc[2], b3[cg4 + 2]);
    o.w = __fadd_rn(acc[3], b3[cg4 + 3]);
    *reinterpret_cast<float4*>(lat + (size_t)(m0 + rg) * 64 + cg4) = o;
  }
}

// ================================ VQ (512 thr) =============================
// Unchanged from round 7 (best-known: 24 waves/CU, conflict-free staging).
__global__ __launch_bounds__(512, 6) void vq_kernel(
    const float* __restrict__ lat, const float* __restrict__ embT,
    const float* __restrict__ En, int* __restrict__ inds,
    float* __restrict__ lossp, float* __restrict__ oh) {
  __shared__ float sL[64 * 68];   // lat_t [64d][68r]
  __shared__ float sE[64 * 132];  // emb_t chunk [64d][132c]
  __shared__ float sEn[128];
  __shared__ float snl[64];
  __shared__ int ridx[64];
  __shared__ float lacc;
  const int t = threadIdx.x;
  const int tx = t & 31, ty = t >> 5;
  const int r0 = ty * 4;
  const int tx4 = tx * 4;
  const int m0 = blockIdx.x * 64;

  for (int v = t; v < 1024; v += 512) {
    const int r = v >> 4, d4 = v & 15;
    const float4 lv =
        *reinterpret_cast<const float4*>(lat + (size_t)(m0 + r) * 64 + 4 * d4);
    float* dst = &sL[(4 * d4) * 68 + r];
    dst[0] = lv.x; dst[68] = lv.y; dst[136] = lv.z; dst[204] = lv.w;
  }
  if (t == 0) lacc = 0.f;
  __syncthreads();
  if (t < 64) {  // numpy pairwise ||lat_r||^2
    float q[8];
#pragma unroll
    for (int j = 0; j < 8; ++j) {
      const float v = sL[j * 68 + t];
      q[j] = __fmul_rn(v, v);
    }
#pragma unroll
    for (int m = 1; m < 8; ++m)
#pragma unroll
      for (int j = 0; j < 8; ++j) {
        const float v = sL[(m * 8 + j) * 68 + t];
        q[j] = __fadd_rn(q[j], __fmul_rn(v, v));
      }
    snl[t] = __fadd_rn(
        __fadd_rn(__fadd_rn(q[0], q[1]), __fadd_rn(q[2], q[3])),
        __fadd_rn(__fadd_rn(q[4], q[5]), __fadd_rn(q[6], q[7])));
  }
  __syncthreads();
  float nl[4];
#pragma unroll
  for (int i = 0; i < 4; ++i) nl[i] = snl[r0 + i];

  float v1[4];
  int i1[4];
#pragma unroll
  for (int i = 0; i < 4; ++i) { v1[i] = FLT_MAX; i1[i] = INT_MAX; }

  for (int ch = 0; ch < 64; ++ch) {  // 8192 codes, 128-col chunks
    const int c0 = ch * 128;
    __syncthreads();
    for (int v = t; v < 2048; v += 512) {
      const int cl = v & 31, d = v >> 5;
      const float4 e = *reinterpret_cast<const float4*>(
          embT + (size_t)d * 8192 + c0 + 4 * cl);
      *reinterpret_cast<float4*>(&sE[d * 132 + 4 * cl]) = e;
    }
    if (t < 128) sEn[t] = En[c0 + t];
    __syncthreads();

    float acc[4][4] = {};
#pragma unroll 4
    for (int d = 0; d < 64; ++d) {  // k-sequential fma chain
      const float4 a = *reinterpret_cast<const float4*>(&sL[d * 68 + r0]);
      const float4 bb = *reinterpret_cast<const float4*>(&sE[d * 132 + tx4]);
      const float av[4] = {a.x, a.y, a.z, a.w};
      const float bv[4] = {bb.x, bb.y, bb.z, bb.w};
#pragma unroll
      for (int i = 0; i < 4; ++i)
#pragma unroll
        for (int j = 0; j < 4; ++j) acc[i][j] = fmaf(av[i], bv[j], acc[i][j]);
    }
#pragma unroll
    for (int j = 0; j < 4; ++j) {
      const float Ec = sEn[tx4 + j];
      const int c = c0 + tx4 + j;
#pragma unroll
      for (int i = 0; i < 4; ++i) {
        const float t1 = __fadd_rn(nl[i], Ec);
        const float s = __fsub_rn(t1, __fmul_rn(2.0f, acc[i][j]));
        if (s < v1[i]) { v1[i] = s; i1[i] = c; }
      }
    }
    const float4 z = make_float4(0.f, 0.f, 0.f, 0.f);
    for (int v = t; v < 2048; v += 512) {
      const int r = v >> 5, c4 = v & 31;
      *reinterpret_cast<float4*>(oh + (size_t)(m0 + r) * 8192 + c0 + 4 * c4) =
          z;
    }
  }

#pragma unroll
  for (int m = 16; m >= 1; m >>= 1) {
#pragma unroll
    for (int i = 0; i < 4; ++i) {
      const float ov = __shfl_xor(v1[i], m);
      const int oi = __shfl_xor(i1[i], m);
      if (ov < v1[i] || (ov == v1[i] && oi < i1[i])) {
        v1[i] = ov; i1[i] = oi;
      }
    }
  }
  if (tx == 0) {
    float ls = 0.f;
#pragma unroll
    for (int i = 0; i < 4; ++i) {
      ridx[r0 + i] = i1[i];
      inds[m0 + r0 + i] = i1[i];
      ls += v1[i];
    }
    atomicAdd(&lacc, ls);
  }
  __syncthreads();
  if (t == 0) lossp[blockIdx.x] = lacc;

  for (int v = t; v < 2048; v += 512) {
    const int r = v >> 5, c4 = v & 31;
    const int ind = ridx[r];
    const int g4 = ind >> 2;
    if ((g4 & 31) == c4) {
      float4 o = make_float4(0.f, 0.f, 0.f, 0.f);
      reinterpret_cast<float*>(&o)[ind & 3] = 1.f;
      *reinterpret_cast<float4*>(oh + (size_t)(m0 + r) * 8192 + 4 * g4) = o;
    }
  }
}

// ================ fused decoder (32 rows, 512 thr, 64.5 KB) ================
__global__ __launch_bounds__(512) void dec_fused(
    const float* __restrict__ emb, const int* __restrict__ inds,
    const float* __restrict__ WT1, const float* __restrict__ b1,
    const float* __restrict__ WT2, const float* __restrict__ b2,
    const float* __restrict__ WTmu, const float* __restrict__ bmu,
    const float* __restrict__ WTlv, const float* __restrict__ blv,
    float* __restrict__ xh, float* __restrict__ xv) {
  __shared__ float sQ[64 * 36];
  __shared__ float sG1[128 * 36];
  __shared__ float sG2[256 * 36];
  const int t = threadIdx.x;
  const int m0 = blockIdx.x * 32;

  for (int v = t; v < 512; v += 512) {  // gather q transposed
    const int k4 = v & 15, r = v >> 4;
    const int id = inds[m0 + r];
    const float4 e =
        *reinterpret_cast<const float4*>(emb + (size_t)id * 64 + 4 * k4);
    float* dst = &sQ[(4 * k4) * 36 + r];
    dst[0] = e.x; dst[36] = e.y; dst[72] = e.z; dst[108] = e.w;
  }
  __syncthreads();

  // L1: K=64, N=128. 32 colgroups (4) x 16 rowgroups (2)
  {
    const int cg4 = (t & 31) * 4, rg2 = (t >> 5) * 2;
    float acc[2][4] = {};
#pragma unroll 8
    for (int k = 0; k < 64; ++k) {
      const float2 a = *reinterpret_cast<const float2*>(&sQ[k * 36 + rg2]);
      const float4 bb =
          *reinterpret_cast<const float4*>(WT1 + (size_t)k * 128 + cg4);
      const float av[2] = {a.x, a.y};
      const float bv[4] = {bb.x, bb.y, bb.z, bb.w};
#pragma unroll
      for (int i = 0; i < 2; ++i)
#pragma unroll
        for (int j = 0; j < 4; ++j) acc[i][j] = fmaf(av[i], bv[j], acc[i][j]);
    }
#pragma unroll
    for (int j = 0; j < 4; ++j) {
      const int col = cg4 + j;
      const float bj = b1[col];
#pragma unroll
      for (int i = 0; i < 2; ++i) {
        const float h = acc[i][j] + bj;
        sG1[col * 36 + rg2 + i] = h > 0.f ? h : 0.f;
      }
    }
  }
  __syncthreads();

  // L2: K=128, N=256. 32 colgroups (8) x 16 rowgroups (2)
  {
    const int cg8 = (t & 31) * 8, rg2 = (t >> 5) * 2;
    float acc[2][8] = {};
#pragma unroll 8
    for (int k = 0; k < 128; ++k) {
      const float2 a = *reinterpret_cast<const float2*>(&sG1[k * 36 + rg2]);
      const float* wr = WT2 + (size_t)k * 256 + cg8;
      const float4 b0 = *reinterpret_cast<const float4*>(wr);
      const float4 b1v = *reinterpret_cast<const float4*>(wr + 4);
      const float av[2] = {a.x, a.y};
      const float bv[8] = {b0.x, b0.y, b0.z, b0.w, b1v.x, b1v.y, b1v.z, b1v.w};
#pragma unroll
      for (int i = 0; i < 2; ++i)
#pragma unroll
        for (int j = 0; j < 8; ++j) acc[i][j] = fmaf(av[i], bv[j], acc[i][j]);
    }
#pragma unroll
    for (int j = 0; j < 8; ++j) {
      const int col = cg8 + j;
      const float bj = b2[col];
#pragma unroll
      for (int i = 0; i < 2; ++i) {
        const float h = acc[i][j] + bj;
        sG2[col * 36 + rg2 + i] = h > 0.f ? h : 0.f;
      }
    }
  }
  __syncthreads();

  // heads: K=256, N=128 each. 32 colgroups (4) x 16 rowgroups (2)
  for (int head = 0; head < 2; ++head) {
    const float* WT = head ? WTlv : WTmu;
    const float* bb_ = head ? blv : bmu;
    float* o = head ? xv : xh;
    const int cg4 = (t & 31) * 4, rg2 = (t >> 5) * 2;
    float acc[2][4] = {};
#pragma unroll 8
    for (int k = 0; k < 256; ++k) {
      const float2 a = *reinterpret_cast<const float2*>(&sG2[k * 36 + rg2]);
      const float4 bb =
          *reinterpret_cast<const float4*>(WT + (size_t)k * 128 + cg4);
      const float av[2] = {a.x, a.y};
      const float bv[4] = {bb.x, bb.y, bb.z, bb.w};
#pragma unroll
      for (int i = 0; i < 2; ++i)
#pragma unroll
        for (int j = 0; j < 4; ++j) acc[i][j] = fmaf(av[i], bv[j], acc[i][j]);
    }
#pragma unroll
    for (int i = 0; i < 2; ++i) {
      float4 ov;
      ov.x = acc[i][0] + bb_[cg4 + 0];
      ov.y = acc[i][1] + bb_[cg4 + 1];
      ov.z = acc[i][2] + bb_[cg4 + 2];
      ov.w = acc[i][3] + bb_[cg4 + 3];
      *reinterpret_cast<float4*>(o + (size_t)(m0 + rg2 + i) * 128 + cg4) = ov;
    }
  }
}

// vq_loss = 2.25 * sum(d_min) / (N*LAT)
__global__ void fin_kernel(const float* __restrict__ lossp,
                           float* __restrict__ outp) {
  const int t = threadIdx.x;  // 64
  double s = 0.0;
  for (int i = t; i < 512; i += 64) s += (double)lossp[i];
#pragma unroll
  for (int m = 32; m >= 1; m >>= 1) s += __shfl_xor(s, m);
  if (t == 0) *outp = (float)(2.25 * s / (32768.0 * 64.0));
}

// ---------------------------------------------------------------------------
extern "C" void kernel_launch(void* const* d_in, const int* in_sizes, int n_in,
                              void* d_out, int out_size, void* d_ws,
                              size_t ws_size, hipStream_t stream) {
  const float* x = (const float*)d_in[0];
  const float* eW1 = (const float*)d_in[1];
  const float* eb1 = (const float*)d_in[2];
  const float* eW2 = (const float*)d_in[3];
  const float* eb2 = (const float*)d_in[4];
  const float* eW3 = (const float*)d_in[5];
  const float* eb3 = (const float*)d_in[6];
  const float* emb = (const float*)d_in[7];
  const float* dW1 = (const float*)d_in[8];
  const float* db1 = (const float*)d_in[9];
  const float* dW2 = (const float*)d_in[10];
  const float* db2 = (const float*)d_in[11];
  const float* dWmu = (const float*)d_in[12];
  const float* dbmu = (const float*)d_in[13];
  const float* dWlv = (const float*)d_in[14];
  const float* dblv = (const float*)d_in[15];

  float* out = (float*)d_out;
  float* xhat = out;                 // [32768,128]
  float* xvar = out + 4194304;       // [32768,128]
  float* oh = out + 8388608;         // [32768,8192]
  float* lossout = out + 276824064;  // scalar

  // ws layout (floats)
  float* lat = (float*)d_ws;             // 2,097,152
  float* En = lat + 2097152;             // 8,192
  float* lossp = En + 8192;              // 512
  int* inds = (int*)(lossp + 512);       // 32,768
  float* embT = (float*)(inds + 32768);  // 524,288  [64][8192]
  float* wt = embT + 524288;             // WT pool
  float* wt1 = wt;                       // [128][256]
  float* wt2 = wt + 32768;               // [256][128]
  float* wt3 = wt + 65536;               // [128][64]
  float* uwt1 = wt + 73728;              // [64][128]
  float* uwt2 = wt + 81920;              // [128][256]
  float* uwtmu = wt + 114688;            // [256][128]
  float* uwtlv = wt + 147456;            // [256][128]

  prep_kernel<<<172, TPB, 0, stream>>>(eW1, eW2, eW3, dW1, dW2, dWmu, dWlv, wt,
                                       emb, embT, En);
  enc_fused<<<1024, 512, 0, stream>>>(x, wt1, wt2, wt3, eb1, eb2, eb3, lat);
  vq_kernel<<<512, 512, 0, stream>>>(lat, embT, En, inds, lossp, oh);
  dec_fused<<<1024, 512, 0, stream>>>(emb, inds, uwt1, db1, uwt2, db2, uwtmu,
                                      dbmu, uwtlv, dblv, xhat, xvar);
  fin_kernel<<<1, 64, 0, stream>>>(lossp, lossout);
}

// Round 9
// 1792.314 us; speedup vs baseline: 1.0254x; 1.0254x over previous
//
#include <hip/hip_runtime.h>
#include <cfloat>
#include <climits>

#define TPB 256

// ---------------------------------------------------------------------------
// Numerics contract (rounds 3-8 PASSED): every matmul output is a
// k-sequential single-accumulator fp32 fmaf chain (k ascending), bias via
// __fadd_rn (encoder), norms via numpy pairwise order,
// d = fl(fl(nl+ne) - fl(2*dot)), argmin strict-< with first-index ties.
// Round-9: enc/dec reverted to round-7 (measured best; round-8's 32-row
// variant halved FMA/load and regressed). vq -> acc[8][8] (128 rows x
// 256-col chunks): 4 ds_read_b128 per 64 FMA instead of 2 per 16 — the
// kernel is LDS-instruction-issue-bound (~12 cyc/b128), so halving
// instr/FMA halves its ~650 us to ~330+overhead. Chains unchanged.
// ---------------------------------------------------------------------------

// =================== prep: W -> WT  and  emb -> embT + En ==================
__global__ __launch_bounds__(TPB) void prep_kernel(
    const float* __restrict__ W1, const float* __restrict__ W2,
    const float* __restrict__ W3, const float* __restrict__ U1,
    const float* __restrict__ U2, const float* __restrict__ Umu,
    const float* __restrict__ Ulv, float* __restrict__ wt,
    const float* __restrict__ emb, float* __restrict__ embT,
    float* __restrict__ En) {
  __shared__ float sB[64 * 68];
  const int b = blockIdx.x;
  const int t = threadIdx.x;
  if (b < 44) {  // weight transpose: WT[k][n] = W[n][k], 64x64 tiles
    const float* src; int R, C, lt; float* dst;
    if (b < 8)       { src = W1;  R = 256; C = 128; dst = wt;          lt = b; }
    else if (b < 16) { src = W2;  R = 128; C = 256; dst = wt + 32768;  lt = b - 8; }
    else if (b < 18) { src = W3;  R = 64;  C = 128; dst = wt + 65536;  lt = b - 16; }
    else if (b < 20) { src = U1;  R = 128; C = 64;  dst = wt + 73728;  lt = b - 18; }
    else if (b < 28) { src = U2;  R = 256; C = 128; dst = wt + 81920;  lt = b - 20; }
    else if (b < 36) { src = Umu; R = 128; C = 256; dst = wt + 114688; lt = b - 28; }
    else             { src = Ulv; R = 128; C = 256; dst = wt + 147456; lt = b - 36; }
    const int tiles_r = R >> 6;
    const int r0 = (lt % tiles_r) << 6, c0 = (lt / tiles_r) << 6;
    for (int v = t; v < 1024; v += TPB) {
      const int c4 = v & 15, r = v >> 4;
      const float4 w = *reinterpret_cast<const float4*>(
          src + (size_t)(r0 + r) * C + c0 + 4 * c4);
      *reinterpret_cast<float4*>(&sB[r * 68 + 4 * c4]) = w;
    }
    __syncthreads();
    for (int v = t; v < 1024; v += TPB) {
      const int r4 = v & 15, c = v >> 4;
      float4 o;
      o.x = sB[(4 * r4 + 0) * 68 + c];
      o.y = sB[(4 * r4 + 1) * 68 + c];
      o.z = sB[(4 * r4 + 2) * 68 + c];
      o.w = sB[(4 * r4 + 3) * 68 + c];
      *reinterpret_cast<float4*>(dst + (size_t)(c0 + c) * R + r0 + 4 * r4) = o;
    }
  } else {  // emb transpose + numpy-pairwise ||e||^2
    const int c0 = (b - 44) * 64;
    for (int v = t; v < 1024; v += TPB) {
      const int d4 = v & 15, r = v >> 4;
      const float4 e = *reinterpret_cast<const float4*>(
          emb + (size_t)(c0 + r) * 64 + 4 * d4);
      *reinterpret_cast<float4*>(&sB[r * 68 + 4 * d4]) = e;
    }
    __syncthreads();
    if (t < 64) {
      const float* row = &sB[t * 68];
      float q[8];
#pragma unroll
      for (int j = 0; j < 8; ++j) q[j] = __fmul_rn(row[j], row[j]);
#pragma unroll
      for (int m = 1; m < 8; ++m)
#pragma unroll
        for (int j = 0; j < 8; ++j) {
          const float v = row[m * 8 + j];
          q[j] = __fadd_rn(q[j], __fmul_rn(v, v));
        }
      En[c0 + t] = __fadd_rn(
          __fadd_rn(__fadd_rn(q[0], q[1]), __fadd_rn(q[2], q[3])),
          __fadd_rn(__fadd_rn(q[4], q[5]), __fadd_rn(q[6], q[7])));
    }
    for (int v = t; v < 1024; v += TPB) {
      const int r4 = v & 15, d = v >> 4;
      float4 o;
      o.x = sB[(4 * r4 + 0) * 68 + d];
      o.y = sB[(4 * r4 + 1) * 68 + d];
      o.z = sB[(4 * r4 + 2) * 68 + d];
      o.w = sB[(4 * r4 + 3) * 68 + d];
      *reinterpret_cast<float4*>(embT + (size_t)d * 8192 + c0 + 4 * r4) = o;
    }
  }
}

// ============== fused encoder (64 rows, 512 thr) — round-7 exact ===========
__global__ __launch_bounds__(512) void enc_fused(
    const float* __restrict__ x, const float* __restrict__ WT1,
    const float* __restrict__ WT2, const float* __restrict__ WT3,
    const float* __restrict__ b1, const float* __restrict__ b2,
    const float* __restrict__ b3, float* __restrict__ lat) {
  __shared__ float sX[128 * 68];
  __shared__ float sH1[256 * 68];
  __shared__ float sH2[128 * 68];
  const int t = threadIdx.x;
  const int m0 = blockIdx.x * 64;

  for (int v = t; v < 2048; v += 512) {  // stage x transposed
    const int k4 = v & 31, r = v >> 5;
    const float4 xv =
        *reinterpret_cast<const float4*>(x + (size_t)(m0 + r) * 128 + 4 * k4);
    float* dst = &sX[(4 * k4) * 68 + r];
    dst[0] = xv.x; dst[68] = xv.y; dst[136] = xv.z; dst[204] = xv.w;
  }
  __syncthreads();

  // L1: K=128, N=256. 32 colgroups (8 cols) x 16 rowgroups (4 rows)
  {
    const int cg8 = (t & 31) * 8, rg4 = (t >> 5) * 4;
    float acc[4][8] = {};
#pragma unroll 8
    for (int k = 0; k < 128; ++k) {
      const float4 a = *reinterpret_cast<const float4*>(&sX[k * 68 + rg4]);
      const float* wr = WT1 + (size_t)k * 256 + cg8;
      const float4 b0 = *reinterpret_cast<const float4*>(wr);
      const float4 b1v = *reinterpret_cast<const float4*>(wr + 4);
      const float av[4] = {a.x, a.y, a.z, a.w};
      const float bv[8] = {b0.x, b0.y, b0.z, b0.w, b1v.x, b1v.y, b1v.z, b1v.w};
#pragma unroll
      for (int i = 0; i < 4; ++i)
#pragma unroll
        for (int j = 0; j < 8; ++j) acc[i][j] = fmaf(av[i], bv[j], acc[i][j]);
    }
#pragma unroll
    for (int j = 0; j < 8; ++j) {
      const int col = cg8 + j;
      const float bj = b1[col];
#pragma unroll
      for (int i = 0; i < 4; ++i) {
        const float h = __fadd_rn(acc[i][j], bj);
        sH1[col * 68 + rg4 + i] = h > 0.f ? h : 0.f;
      }
    }
  }
  __syncthreads();

  // L2: K=256, N=128. 32 colgroups (4 cols) x 16 rowgroups (4 rows)
  {
    const int cg4 = (t & 31) * 4, rg4 = (t >> 5) * 4;
    float acc[4][4] = {};
#pragma unroll 8
    for (int k = 0; k < 256; ++k) {
      const float4 a = *reinterpret_cast<const float4*>(&sH1[k * 68 + rg4]);
      const float4 bb =
          *reinterpret_cast<const float4*>(WT2 + (size_t)k * 128 + cg4);
      const float av[4] = {a.x, a.y, a.z, a.w};
      const float bv[4] = {bb.x, bb.y, bb.z, bb.w};
#pragma unroll
      for (int i = 0; i < 4; ++i)
#pragma unroll
        for (int j = 0; j < 4; ++j) acc[i][j] = fmaf(av[i], bv[j], acc[i][j]);
    }
#pragma unroll
    for (int j = 0; j < 4; ++j) {
      const int col = cg4 + j;
      const float bj = b2[col];
#pragma unroll
      for (int i = 0; i < 4; ++i) {
        const float h = __fadd_rn(acc[i][j], bj);
        sH2[col * 68 + rg4 + i] = h > 0.f ? h : 0.f;
      }
    }
  }
  __syncthreads();

  // L3: K=128, N=64. 16 colgroups (4 cols) x 32 rowgroups (2 rows) -> lat
  {
    const int cg4 = (t & 15) * 4, rg2 = (t >> 4) * 2;
    float acc[2][4] = {};
#pragma unroll 8
    for (int k = 0; k < 128; ++k) {
      const float2 a = *reinterpret_cast<const float2*>(&sH2[k * 68 + rg2]);
      const float4 bb =
          *reinterpret_cast<const float4*>(WT3 + (size_t)k * 64 + cg4);
      const float av[2] = {a.x, a.y};
      const float bv[4] = {bb.x, bb.y, bb.z, bb.w};
#pragma unroll
      for (int i = 0; i < 2; ++i)
#pragma unroll
        for (int j = 0; j < 4; ++j) acc[i][j] = fmaf(av[i], bv[j], acc[i][j]);
    }
#pragma unroll
    for (int i = 0; i < 2; ++i) {
      float4 o;
      o.x = __fadd_rn(acc[i][0], b3[cg4 + 0]);
      o.y = __fadd_rn(acc[i][1], b3[cg4 + 1]);
      o.z = __fadd_rn(acc[i][2], b3[cg4 + 2]);
      o.w = __fadd_rn(acc[i][3], b3[cg4 + 3]);
      *reinterpret_cast<float4*>(lat + (size_t)(m0 + rg2 + i) * 64 + cg4) = o;
    }
  }
}

// ================================ VQ (512 thr) =============================
// 128 rows/block, 256-col LDS-staged chunks, acc[8][8]: per d per thread
// 2 broadcast b128 A-reads + 2 stride-4 b128 B-reads for 64 FMAs (0.0625
// LDS-instr/FMA, half of round-7). Rows = {r0..r0+3, 64+r0..}, cols =
// {c..c+3, 128+c..} so every b128 keeps the proven conflict-free pattern.
// ~102 KB LDS -> 1 block/CU, 8 waves. Chains/visit order unchanged.
__global__ __launch_bounds__(512, 2) void vq_kernel(
    const float* __restrict__ lat, const float* __restrict__ embT,
    const float* __restrict__ En, int* __restrict__ inds,
    float* __restrict__ lossp, float* __restrict__ oh) {
  __shared__ float sL[64 * 132];  // lat_t [64d][132r] (128 rows + pad)
  __shared__ float sE[64 * 260];  // emb_t chunk [64d][260c] (256 cols + pad)
  __shared__ float sEn[256];
  __shared__ float snl[128];
  __shared__ int ridx[128];
  __shared__ float lacc;
  const int t = threadIdx.x;
  const int tx = t & 31, ty = t >> 5;  // colgroup, rowgroup
  const int r0 = ty * 4;               // rows r0..r0+3 and 64+r0..64+r0+3
  const int tx4 = tx * 4;              // cols tx4.. and 128+tx4..
  const int m0 = blockIdx.x * 128;

  for (int v = t; v < 2048; v += 512) {  // stage lat transposed (128 rows)
    const int r = v >> 4, d4 = v & 15;
    const float4 lv =
        *reinterpret_cast<const float4*>(lat + (size_t)(m0 + r) * 64 + 4 * d4);
    float* dst = &sL[(4 * d4) * 132 + r];
    dst[0] = lv.x; dst[132] = lv.y; dst[264] = lv.z; dst[396] = lv.w;
  }
  if (t == 0) lacc = 0.f;
  __syncthreads();
  if (t < 128) {  // numpy pairwise ||lat_r||^2
    float q[8];
#pragma unroll
    for (int j = 0; j < 8; ++j) {
      const float v = sL[j * 132 + t];
      q[j] = __fmul_rn(v, v);
    }
#pragma unroll
    for (int m = 1; m < 8; ++m)
#pragma unroll
      for (int j = 0; j < 8; ++j) {
        const float v = sL[(m * 8 + j) * 132 + t];
        q[j] = __fadd_rn(q[j], __fmul_rn(v, v));
      }
    snl[t] = __fadd_rn(
        __fadd_rn(__fadd_rn(q[0], q[1]), __fadd_rn(q[2], q[3])),
        __fadd_rn(__fadd_rn(q[4], q[5]), __fadd_rn(q[6], q[7])));
  }
  __syncthreads();
  float nl[8];
#pragma unroll
  for (int i = 0; i < 4; ++i) {
    nl[i] = snl[r0 + i];
    nl[4 + i] = snl[64 + r0 + i];
  }

  float v1[8];
  int i1[8];
#pragma unroll
  for (int i = 0; i < 8; ++i) { v1[i] = FLT_MAX; i1[i] = INT_MAX; }

  for (int ch = 0; ch < 32; ++ch) {  // 8192 codes, 256-col chunks
    const int c0 = ch * 256;
    __syncthreads();
    for (int v = t; v < 4096; v += 512) {  // stage sE: coalesced, b128 writes
      const int cl = v & 63, d = v >> 6;
      const float4 e = *reinterpret_cast<const float4*>(
          embT + (size_t)d * 8192 + c0 + 4 * cl);
      *reinterpret_cast<float4*>(&sE[d * 260 + 4 * cl]) = e;
    }
    if (t < 256) sEn[t] = En[c0 + t];
    __syncthreads();

    float acc[8][8] = {};
#pragma unroll 2
    for (int d = 0; d < 64; ++d) {  // k-sequential fma chain per output
      const float* lrow = &sL[d * 132];
      const float* erow = &sE[d * 260];
      const float4 a0 = *reinterpret_cast<const float4*>(lrow + r0);
      const float4 a1 = *reinterpret_cast<const float4*>(lrow + 64 + r0);
      const float4 b0 = *reinterpret_cast<const float4*>(erow + tx4);
      const float4 b1v = *reinterpret_cast<const float4*>(erow + 128 + tx4);
      const float av[8] = {a0.x, a0.y, a0.z, a0.w, a1.x, a1.y, a1.z, a1.w};
      const float bv[8] = {b0.x, b0.y, b0.z, b0.w, b1v.x, b1v.y, b1v.z, b1v.w};
#pragma unroll
      for (int i = 0; i < 8; ++i)
#pragma unroll
        for (int j = 0; j < 8; ++j) acc[i][j] = fmaf(av[i], bv[j], acc[i][j]);
    }
    // candidates ascending per thread: group0 cols (tx4+j) then group1
    // (128+tx4+j); strict '<' keeps first occurrence (np.argmin ties).
#pragma unroll
    for (int g = 0; g < 2; ++g)
#pragma unroll
      for (int j = 0; j < 4; ++j) {
        const int cl = g * 128 + tx4 + j;
        const float Ec = sEn[cl];
        const int c = c0 + cl;
#pragma unroll
        for (int i = 0; i < 8; ++i) {
          const float t1 = __fadd_rn(nl[i], Ec);
          const float s = __fsub_rn(t1, __fmul_rn(2.0f, acc[i][g * 4 + j]));
          if (s < v1[i]) { v1[i] = s; i1[i] = c; }
        }
      }
    // spread one_hot zeros for this chunk (128 rows x 64 float4-cols)
    const float4 z = make_float4(0.f, 0.f, 0.f, 0.f);
    for (int v = t; v < 8192; v += 512) {
      const int r = v >> 6, c4 = v & 63;
      *reinterpret_cast<float4*>(oh + (size_t)(m0 + r) * 8192 + c0 + 4 * c4) =
          z;
    }
  }

  // merge across the 32 col-group lanes (xor<=16 stays in each 32-lane half;
  // halves of a wave hold different rowgroups), first-index ties
#pragma unroll
  for (int m = 16; m >= 1; m >>= 1) {
#pragma unroll
    for (int i = 0; i < 8; ++i) {
      const float ov = __shfl_xor(v1[i], m);
      const int oi = __shfl_xor(i1[i], m);
      if (ov < v1[i] || (ov == v1[i] && oi < i1[i])) {
        v1[i] = ov; i1[i] = oi;
      }
    }
  }
  if (tx == 0) {
    float ls = 0.f;
#pragma unroll
    for (int i = 0; i < 8; ++i) {
      const int r = (i < 4) ? (r0 + i) : (64 + r0 + i - 4);
      ridx[r] = i1[i];
      inds[m0 + r] = i1[i];
      ls += v1[i];  // d_min == ||q-lat||^2
    }
    atomicAdd(&lacc, ls);
  }
  __syncthreads();
  if (t == 0) lossp[blockIdx.x] = lacc;

  // patch ones: same (r, c4-slot) owner thread that wrote the zero earlier
  // (same-thread same-address program order, no fence needed)
  for (int v = t; v < 8192; v += 512) {
    const int r = v >> 6, c4 = v & 63;
    const int ind = ridx[r];
    const int g4 = ind >> 2;  // global float4 col 0..2047
    if ((g4 & 63) == c4) {
      float4 o = make_float4(0.f, 0.f, 0.f, 0.f);
      reinterpret_cast<float*>(&o)[ind & 3] = 1.f;
      *reinterpret_cast<float4*>(oh + (size_t)(m0 + r) * 8192 + 4 * g4) = o;
    }
  }
}

// ============== fused decoder (64 rows, 512 thr) — round-7 exact ===========
__global__ __launch_bounds__(512) void dec_fused(
    const float* __restrict__ emb, const int* __restrict__ inds,
    const float* __restrict__ WT1, const float* __restrict__ b1,
    const float* __restrict__ WT2, const float* __restrict__ b2,
    const float* __restrict__ WTmu, const float* __restrict__ bmu,
    const float* __restrict__ WTlv, const float* __restrict__ blv,
    float* __restrict__ xh, float* __restrict__ xv) {
  __shared__ float sQ[64 * 68];
  __shared__ float sG1[128 * 68];
  __shared__ float sG2[256 * 68];
  const int t = threadIdx.x;
  const int m0 = blockIdx.x * 64;

  for (int v = t; v < 1024; v += 512) {  // gather q transposed
    const int k4 = v & 15, r = v >> 4;
    const int id = inds[m0 + r];
    const float4 e =
        *reinterpret_cast<const float4*>(emb + (size_t)id * 64 + 4 * k4);
    float* dst = &sQ[(4 * k4) * 68 + r];
    dst[0] = e.x; dst[68] = e.y; dst[136] = e.z; dst[204] = e.w;
  }
  __syncthreads();

  // L1: K=64, N=128. 32 colgroups (4) x 16 rowgroups (4)
  {
    const int cg4 = (t & 31) * 4, rg4 = (t >> 5) * 4;
    float acc[4][4] = {};
#pragma unroll 8
    for (int k = 0; k < 64; ++k) {
      const float4 a = *reinterpret_cast<const float4*>(&sQ[k * 68 + rg4]);
      const float4 bb =
          *reinterpret_cast<const float4*>(WT1 + (size_t)k * 128 + cg4);
      const float av[4] = {a.x, a.y, a.z, a.w};
      const float bv[4] = {bb.x, bb.y, bb.z, bb.w};
#pragma unroll
      for (int i = 0; i < 4; ++i)
#pragma unroll
        for (int j = 0; j < 4; ++j) acc[i][j] = fmaf(av[i], bv[j], acc[i][j]);
    }
#pragma unroll
    for (int j = 0; j < 4; ++j) {
      const int col = cg4 + j;
      const float bj = b1[col];
#pragma unroll
      for (int i = 0; i < 4; ++i) {
        const float h = acc[i][j] + bj;
        sG1[col * 68 + rg4 + i] = h > 0.f ? h : 0.f;
      }
    }
  }
  __syncthreads();

  // L2: K=128, N=256. 32 colgroups (8) x 16 rowgroups (4)
  {
    const int cg8 = (t & 31) * 8, rg4 = (t >> 5) * 4;
    float acc[4][8] = {};
#pragma unroll 8
    for (int k = 0; k < 128; ++k) {
      const float4 a = *reinterpret_cast<const float4*>(&sG1[k * 68 + rg4]);
      const float* wr = WT2 + (size_t)k * 256 + cg8;
      const float4 b0 = *reinterpret_cast<const float4*>(wr);
      const float4 b1v = *reinterpret_cast<const float4*>(wr + 4);
      const float av[4] = {a.x, a.y, a.z, a.w};
      const float bv[8] = {b0.x, b0.y, b0.z, b0.w, b1v.x, b1v.y, b1v.z, b1v.w};
#pragma unroll
      for (int i = 0; i < 4; ++i)
#pragma unroll
        for (int j = 0; j < 8; ++j) acc[i][j] = fmaf(av[i], bv[j], acc[i][j]);
    }
#pragma unroll
    for (int j = 0; j < 8; ++j) {
      const int col = cg8 + j;
      const float bj = b2[col];
#pragma unroll
      for (int i = 0; i < 4; ++i) {
        const float h = acc[i][j] + bj;
        sG2[col * 68 + rg4 + i] = h > 0.f ? h : 0.f;
      }
    }
  }
  __syncthreads();

  // heads: K=256, N=128 each. 32 colgroups (4) x 16 rowgroups (4)
  for (int head = 0; head < 2; ++head) {
    const float* WT = head ? WTlv : WTmu;
    const float* bb_ = head ? blv : bmu;
    float* o = head ? xv : xh;
    const int cg4 = (t & 31) * 4, rg4 = (t >> 5) * 4;
    float acc[4][4] = {};
#pragma unroll 8
    for (int k = 0; k < 256; ++k) {
      const float4 a = *reinterpret_cast<const float4*>(&sG2[k * 68 + rg4]);
      const float4 bb =
          *reinterpret_cast<const float4*>(WT + (size_t)k * 128 + cg4);
      const float av[4] = {a.x, a.y, a.z, a.w};
      const float bv[4] = {bb.x, bb.y, bb.z, bb.w};
#pragma unroll
      for (int i = 0; i < 4; ++i)
#pragma unroll
        for (int j = 0; j < 4; ++j) acc[i][j] = fmaf(av[i], bv[j], acc[i][j]);
    }
#pragma unroll
    for (int i = 0; i < 4; ++i) {
      float4 ov;
      ov.x = acc[i][0] + bb_[cg4 + 0];
      ov.y = acc[i][1] + bb_[cg4 + 1];
      ov.z = acc[i][2] + bb_[cg4 + 2];
      ov.w = acc[i][3] + bb_[cg4 + 3];
      *reinterpret_cast<float4*>(o + (size_t)(m0 + rg4 + i) * 128 + cg4) = ov;
    }
  }
}

// vq_loss = 2.25 * sum(d_min) / (N*LAT)
__global__ void fin_kernel(const float* __restrict__ lossp,
                           float* __restrict__ outp) {
  const int t = threadIdx.x;  // 64
  double s = 0.0;
  for (int i = t; i < 256; i += 64) s += (double)lossp[i];
#pragma unroll
  for (int m = 32; m >= 1; m >>= 1) s += __shfl_xor(s, m);
  if (t == 0) *outp = (float)(2.25 * s / (32768.0 * 64.0));
}

// ---------------------------------------------------------------------------
extern "C" void kernel_launch(void* const* d_in, const int* in_sizes, int n_in,
                              void* d_out, int out_size, void* d_ws,
                              size_t ws_size, hipStream_t stream) {
  const float* x = (const float*)d_in[0];
  const float* eW1 = (const float*)d_in[1];
  const float* eb1 = (const float*)d_in[2];
  const float* eW2 = (const float*)d_in[3];
  const float* eb2 = (const float*)d_in[4];
  const float* eW3 = (const float*)d_in[5];
  const float* eb3 = (const float*)d_in[6];
  const float* emb = (const float*)d_in[7];
  const float* dW1 = (const float*)d_in[8];
  const float* db1 = (const float*)d_in[9];
  const float* dW2 = (const float*)d_in[10];
  const float* db2 = (const float*)d_in[11];
  const float* dWmu = (const float*)d_in[12];
  const float* dbmu = (const float*)d_in[13];
  const float* dWlv = (const float*)d_in[14];
  const float* dblv = (const float*)d_in[15];

  float* out = (float*)d_out;
  float* xhat = out;                 // [32768,128]
  float* xvar = out + 4194304;       // [32768,128]
  float* oh = out + 8388608;         // [32768,8192]
  float* lossout = out + 276824064;  // scalar

  // ws layout (floats)
  float* lat = (float*)d_ws;             // 2,097,152
  float* En = lat + 2097152;             // 8,192
  float* lossp = En + 8192;              // 512
  int* inds = (int*)(lossp + 512);       // 32,768
  float* embT = (float*)(inds + 32768);  // 524,288  [64][8192]
  float* wt = embT + 524288;             // WT pool
  float* wt1 = wt;                       // [128][256]
  float* wt2 = wt + 32768;               // [256][128]
  float* wt3 = wt + 65536;               // [128][64]
  float* uwt1 = wt + 73728;              // [64][128]
  float* uwt2 = wt + 81920;              // [128][256]
  float* uwtmu = wt + 114688;            // [256][128]
  float* uwtlv = wt + 147456;            // [256][128]

  prep_kernel<<<172, TPB, 0, stream>>>(eW1, eW2, eW3, dW1, dW2, dWmu, dWlv, wt,
                                       emb, embT, En);
  enc_fused<<<512, 512, 0, stream>>>(x, wt1, wt2, wt3, eb1, eb2, eb3, lat);
  vq_kernel<<<256, 512, 0, stream>>>(lat, embT, En, inds, lossp, oh);
  dec_fused<<<512, 512, 0, stream>>>(emb, inds, uwt1, db1, uwt2, db2, uwtmu,
                                     dbmu, uwtlv, dblv, xhat, xvar);
  fin_kernel<<<1, 64, 0, stream>>>(lossp, lossout);
}